// Round 3
// baseline (181.756 us; speedup 1.0000x reference)
//
#include <hip/hip_runtime.h>

// GPLoss: gradient-profile loss, scalar output.
// ws layout: colPart f32[96*NS][6][512] ; rowPart f32[96*NS][2] ; dblk f64[192]
//   NS = strips/plane (16 preferred, 8 fallback). Strip = 4 waves * RPW rows.

__device__ __forceinline__ float cos_sim(float dot, float sx, float sr){
  float nx = fmaxf(sqrtf(sx), 1e-12f);
  float nr = fmaxf(sqrtf(sr), 1e-12f);
  return dot / (nx * nr);
}

template<int RPW>   // rows per wave; strip = 4*RPW rows; NS = 512/(4*RPW)
__global__ __launch_bounds__(256, 3) void gp_main(
    const float* __restrict__ X, const float* __restrict__ R,
    float* __restrict__ colPart, float* __restrict__ rowPart)
{
  constexpr int NS = 512 / (4 * RPW);
  const int bid = blockIdx.x;
  const int p = bid / NS;          // plane 0..95
  const int s = bid % NS;          // strip
  const int tid = threadIdx.x;
  const int w = tid >> 6, l = tid & 63;

  const size_t plane = (size_t)p * (512u * 512u);
  const float* xp = X + plane;
  const float* rp = R + plane;

  const int base = s * (4 * RPW) + w * RPW;   // first row this wave owns
  const int c0 = 8 * l;                        // lane owns cols 8l..8l+7
  const int nl = (l + 1) & 63;
  const bool lastlane = (l == 63);

  // column accumulators (48 regs)
  float cv0[8], cv1[8], cv2[8], ch0[8], ch1[8], ch2[8];
  #pragma unroll
  for (int j = 0; j < 8; ++j){
    cv0[j]=0.f; cv1[j]=0.f; cv2[j]=0.f;
    ch0[j]=0.f; ch1[j]=0.f; ch2[j]=0.f;
  }
  float brsum_v = 0.f, brsum_h = 0.f;

  // current row registers
  const float* x0p = xp + (size_t)base * 512 + c0;
  const float* r0p = rp + (size_t)base * 512 + c0;
  float4 xa = *(const float4*)(x0p),     xb = *(const float4*)(x0p + 4);
  float4 ra = *(const float4*)(r0p),     rb = *(const float4*)(r0p + 4);

  for (int hb = 0; hb < RPW; hb += 4){
    float rv[4][3], rh[4][3];
    #pragma unroll
    for (int k = 0; k < 4; ++k){ rv[k][0]=rv[k][1]=rv[k][2]=0.f; rh[k][0]=rh[k][1]=rh[k][2]=0.f; }

    #pragma unroll
    for (int k = 0; k < 4; ++k){
      const int h  = base + hb + k;
      const int hn = (h + 1 < 512) ? (h + 1) : 511;
      const float* xn = xp + (size_t)hn * 512 + c0;
      const float* rn = rp + (size_t)hn * 512 + c0;
      const float4 nxa = *(const float4*)(xn), nxb = *(const float4*)(xn + 4);
      const float4 nra = *(const float4*)(rn), nrb = *(const float4*)(rn + 4);

      const float aX[8] = {xa.x,xa.y,xa.z,xa.w,xb.x,xb.y,xb.z,xb.w};
      const float aR[8] = {ra.x,ra.y,ra.z,ra.w,rb.x,rb.y,rb.z,rb.w};

      // ---- f_v on current row: dv[c] = x[c] - x[c+1]
      const float nXx = __shfl(xa.x, nl, 64);
      const float nRx = __shfl(ra.x, nl, 64);
      float dv[8], ev[8];
      #pragma unroll
      for (int j = 0; j < 7; ++j){ dv[j] = aX[j] - aX[j+1]; ev[j] = aR[j] - aR[j+1]; }
      dv[7] = lastlane ? 0.f : (aX[7] - nXx);   // col 511 excluded
      ev[7] = lastlane ? 0.f : (aR[7] - nRx);
      #pragma unroll
      for (int j = 0; j < 8; ++j){
        rv[k][0] = fmaf(dv[j], ev[j], rv[k][0]);
        rv[k][1] = fmaf(dv[j], dv[j], rv[k][1]);
        rv[k][2] = fmaf(ev[j], ev[j], rv[k][2]);
        cv0[j]   = fmaf(dv[j], ev[j], cv0[j]);
        cv1[j]   = fmaf(dv[j], dv[j], cv1[j]);
        cv2[j]   = fmaf(ev[j], ev[j], cv2[j]);
      }

      // ---- f_h between row h and h+1 (rows 0..510 only)
      if (h < 511){
        const float bX[8] = {nxa.x,nxa.y,nxa.z,nxa.w,nxb.x,nxb.y,nxb.z,nxb.w};
        const float bR[8] = {nra.x,nra.y,nra.z,nra.w,nrb.x,nrb.y,nrb.z,nrb.w};
        float dh[8], eh[8];
        #pragma unroll
        for (int j = 0; j < 8; ++j){ dh[j] = aX[j] - bX[j]; eh[j] = aR[j] - bR[j]; }
        #pragma unroll
        for (int j = 0; j < 8; ++j){
          rh[k][0] = fmaf(dh[j], eh[j], rh[k][0]);
          rh[k][1] = fmaf(dh[j], dh[j], rh[k][1]);
          rh[k][2] = fmaf(eh[j], eh[j], rh[k][2]);
          ch0[j]   = fmaf(dh[j], eh[j], ch0[j]);
          ch1[j]   = fmaf(dh[j], dh[j], ch1[j]);
          ch2[j]   = fmaf(eh[j], eh[j], ch2[j]);
        }
      }
      xa = nxa; xb = nxb; ra = nra; rb = nrb;
    }

    // batched butterfly: 24 independent chains, latency hidden by ILP
    #pragma unroll
    for (int m = 1; m < 64; m <<= 1){
      #pragma unroll
      for (int k = 0; k < 4; ++k){
        #pragma unroll
        for (int q = 0; q < 3; ++q){
          rv[k][q] += __shfl_xor(rv[k][q], m, 64);
          rh[k][q] += __shfl_xor(rh[k][q], m, 64);
        }
      }
    }
    #pragma unroll
    for (int k = 0; k < 4; ++k){
      brsum_v += cos_sim(rv[k][0], rv[k][1], rv[k][2]);
      if (base + hb + k < 511) brsum_h += cos_sim(rh[k][0], rh[k][1], rh[k][2]);
    }
  }

  // ---- block-level combine
  __shared__ float lcol[6 * 512];   // 12 KB
  __shared__ float rs[4][2];
  for (int i = tid; i < 6 * 512; i += 256) lcol[i] = 0.f;
  if (l == 0){ rs[w][0] = brsum_v; rs[w][1] = brsum_h; }
  __syncthreads();
  #pragma unroll
  for (int j = 0; j < 8; ++j){
    atomicAdd(&lcol[0*512 + c0 + j], cv0[j]);
    atomicAdd(&lcol[1*512 + c0 + j], cv1[j]);
    atomicAdd(&lcol[2*512 + c0 + j], cv2[j]);
    atomicAdd(&lcol[3*512 + c0 + j], ch0[j]);
    atomicAdd(&lcol[4*512 + c0 + j], ch1[j]);
    atomicAdd(&lcol[5*512 + c0 + j], ch2[j]);
  }
  __syncthreads();
  float* slot = colPart + (size_t)bid * (6 * 512);
  for (int i = tid; i < 6 * 512; i += 256) slot[i] = lcol[i];
  if (tid == 0){
    rowPart[bid*2+0] = rs[0][0]+rs[1][0]+rs[2][0]+rs[3][0];
    rowPart[bid*2+1] = rs[0][1]+rs[1][1]+rs[2][1]+rs[3][1];
  }
}

template<int NS>
__global__ __launch_bounds__(256) void gp_cols(
    const float* __restrict__ colPart, double* __restrict__ dblk)
{
  const int p = blockIdx.x >> 1;
  const int f = blockIdx.x & 1;    // 0 = fv, 1 = fh
  const int tid = threadIdx.x;
  double acc = 0.0;
  for (int c = tid; c < 512; c += 256){
    float d = 0.f, a = 0.f, b = 0.f;
    #pragma unroll
    for (int s = 0; s < NS; ++s){
      const float* sp = colPart + ((size_t)(p*NS + s) * 6 + f*3) * 512;
      d += sp[c]; a += sp[512 + c]; b += sp[1024 + c];
    }
    acc += (double)cos_sim(d, a, b);   // fv col 511: 0/eps^2 = 0, harmless
  }
  #pragma unroll
  for (int m = 1; m < 64; m <<= 1) acc += __shfl_xor(acc, m, 64);
  __shared__ double ls[4];
  const int w = tid >> 6, l = tid & 63;
  if (l == 0) ls[w] = acc;
  __syncthreads();
  if (tid == 0) dblk[blockIdx.x] = ls[0] + ls[1] + ls[2] + ls[3];
}

__global__ __launch_bounds__(256) void gp_fin(
    const double* __restrict__ dblk, const float* __restrict__ rowPart,
    int nblk, float* __restrict__ out)
{
  const int tid = threadIdx.x;
  double rv = 0, rh = 0, cv = 0, ch = 0;
  for (int i = tid; i < nblk; i += 256){
    rv += (double)rowPart[2*i];
    rh += (double)rowPart[2*i+1];
  }
  for (int i = tid; i < 192; i += 256){
    if (i & 1) ch += dblk[i]; else cv += dblk[i];
  }
  #pragma unroll
  for (int m = 1; m < 64; m <<= 1){
    rv += __shfl_xor(rv, m, 64); rh += __shfl_xor(rh, m, 64);
    cv += __shfl_xor(cv, m, 64); ch += __shfl_xor(ch, m, 64);
  }
  __shared__ double ls[4][4];
  const int w = tid >> 6, l = tid & 63;
  if (l == 0){ ls[w][0]=rv; ls[w][1]=rh; ls[w][2]=cv; ls[w][3]=ch; }
  __syncthreads();
  if (tid == 0){
    double RV=0, RH=0, CV=0, CH=0;
    #pragma unroll
    for (int i = 0; i < 4; ++i){ RV+=ls[i][0]; RH+=ls[i][1]; CV+=ls[i][2]; CH+=ls[i][3]; }
    const double t = RV/512.0 + RH/511.0 + CV/511.0 + CH/512.0;
    out[0] = (float)(-t / 32.0);
  }
}

extern "C" void kernel_launch(void* const* d_in, const int* in_sizes, int n_in,
                              void* d_out, int out_size, void* d_ws, size_t ws_size,
                              hipStream_t stream) {
  const float* X = (const float*)d_in[0];
  const float* R = (const float*)d_in[1];
  float* out = (float*)d_out;

  const size_t need16 = (size_t)96*16*6*512*4 + (size_t)96*16*2*4 + 192*8;

  if (ws_size >= need16){
    constexpr int NS = 16;
    float*  colPart = (float*)d_ws;
    float*  rowPart = colPart + (size_t)96*NS*6*512;
    double* dblk    = (double*)(rowPart + (size_t)96*NS*2);
    gp_main<8><<<dim3(96*NS), dim3(256), 0, stream>>>(X, R, colPart, rowPart);
    gp_cols<NS><<<dim3(192), dim3(256), 0, stream>>>(colPart, dblk);
    gp_fin<<<dim3(1), dim3(256), 0, stream>>>(dblk, rowPart, 96*NS, out);
  } else {
    constexpr int NS = 8;
    float*  colPart = (float*)d_ws;
    float*  rowPart = colPart + (size_t)96*NS*6*512;
    double* dblk    = (double*)(rowPart + (size_t)96*NS*2);
    gp_main<16><<<dim3(96*NS), dim3(256), 0, stream>>>(X, R, colPart, rowPart);
    gp_cols<NS><<<dim3(192), dim3(256), 0, stream>>>(colPart, dblk);
    gp_fin<<<dim3(1), dim3(256), 0, stream>>>(dblk, rowPart, 96*NS, out);
  }
}

// Round 4
// 85.439 us; speedup vs baseline: 2.1273x; 2.1273x over previous
//
#include <hip/hip_runtime.h>

// GPLoss: gradient-profile loss, scalar output. Two-pass, register-light.
// ws: colPart f32[768][6][512] (9.44 MB) ; rowPart f32[768][2] ; dblk f64[192]

__device__ __forceinline__ float cos_sim(float dot, float sx, float sr){
  float nx = fmaxf(sqrtf(sx), 1e-12f);
  float nr = fmaxf(sqrtf(sr), 1e-12f);
  return dot / (nx * nr);
}

// ---------------- pass 1: row cosines (f_v and f_h row stats) ----------------
// 96 planes x 8 strips(64 rows); 4 waves/block, wave owns 16 rows (+1 halo).
// Lane owns 8 contiguous cols. No column state -> ~55 live VGPRs, no spills.
__global__ __launch_bounds__(256) void gp_rows(
    const float* __restrict__ X, const float* __restrict__ R,
    float* __restrict__ rowPart)
{
  const int bid = blockIdx.x;
  const int p = bid >> 3, s = bid & 7;
  const int tid = threadIdx.x, w = tid >> 6, l = tid & 63;
  const size_t plane = (size_t)p * (512u*512u);
  const float* xp = X + plane;
  const float* rp = R + plane;
  const int base = s*64 + w*16;
  const int c0 = 8*l;
  const int nl = (l+1) & 63;
  const bool lastlane = (l == 63);

  float rsv = 0.f, rsh = 0.f;

  const float* xr = xp + (size_t)base*512 + c0;
  const float* rr = rp + (size_t)base*512 + c0;
  float4 xa = *(const float4*)xr, xb = *(const float4*)(xr+4);
  float4 ra = *(const float4*)rr, rb = *(const float4*)(rr+4);

  #pragma unroll 2
  for (int k = 0; k < 16; ++k){
    const int h  = base + k;
    const int hn = (h+1 < 512) ? h+1 : 511;
    const float* xn = xp + (size_t)hn*512 + c0;
    const float* rn = rp + (size_t)hn*512 + c0;
    const float4 nxa = *(const float4*)xn, nxb = *(const float4*)(xn+4);
    const float4 nra = *(const float4*)rn, nrb = *(const float4*)(rn+4);

    const float nX = __shfl(xa.x, nl, 64);
    const float nR = __shfl(ra.x, nl, 64);

    const float aX[8] = {xa.x,xa.y,xa.z,xa.w, xb.x,xb.y,xb.z,xb.w};
    const float aR[8] = {ra.x,ra.y,ra.z,ra.w, rb.x,rb.y,rb.z,rb.w};
    const float bX[8] = {nxa.x,nxa.y,nxa.z,nxa.w, nxb.x,nxb.y,nxb.z,nxb.w};
    const float bR[8] = {nra.x,nra.y,nra.z,nra.w, nrb.x,nrb.y,nrb.z,nrb.w};

    float s0=0.f,s1=0.f,s2=0.f,s3=0.f,s4=0.f,s5=0.f;
    #pragma unroll
    for (int j = 0; j < 8; ++j){
      const float dv = (j<7) ? (aX[j]-aX[j+1]) : (lastlane ? 0.f : aX[7]-nX);
      const float ev = (j<7) ? (aR[j]-aR[j+1]) : (lastlane ? 0.f : aR[7]-nR);
      s0 = fmaf(dv,ev,s0); s1 = fmaf(dv,dv,s1); s2 = fmaf(ev,ev,s2);
      const float dh = aX[j]-bX[j];       // h==511: b==a -> 0, discarded below
      const float eh = aR[j]-bR[j];
      s3 = fmaf(dh,eh,s3); s4 = fmaf(dh,dh,s4); s5 = fmaf(eh,eh,s5);
    }
    #pragma unroll
    for (int m = 1; m < 64; m <<= 1){   // 6 independent chains, ILP=6
      s0 += __shfl_xor(s0,m,64); s1 += __shfl_xor(s1,m,64); s2 += __shfl_xor(s2,m,64);
      s3 += __shfl_xor(s3,m,64); s4 += __shfl_xor(s4,m,64); s5 += __shfl_xor(s5,m,64);
    }
    rsv += cos_sim(s0,s1,s2);
    if (h < 511) rsh += cos_sim(s3,s4,s5);
    xa=nxa; xb=nxb; ra=nra; rb=nrb;
  }

  __shared__ float rs[4][2];
  if (l == 0){ rs[w][0]=rsv; rs[w][1]=rsh; }
  __syncthreads();
  if (tid == 0){
    rowPart[2*bid+0] = rs[0][0]+rs[1][0]+rs[2][0]+rs[3][0];
    rowPart[2*bid+1] = rs[0][1]+rs[1][1]+rs[2][1]+rs[3][1];
  }
}

// ---------------- pass 2: column partial stats, pure per-thread --------------
// 96 planes x 8 bands(64 rows); 256 threads, thread owns cols {2t, 2t+1}.
// Coalesced float2 row loads; 1 shfl/array/row for the f_v neighbor.
__global__ __launch_bounds__(256) void gp_colacc(
    const float* __restrict__ X, const float* __restrict__ R,
    float* __restrict__ colPart)
{
  const int bid = blockIdx.x;
  const int p = bid >> 3, b = bid & 7;
  const int tid = threadIdx.x;
  const int l = tid & 63;
  const int nl = (l+1) & 63;
  const size_t plane = (size_t)p * (512u*512u);
  const float* xp = X + plane;
  const float* rp = R + plane;
  const int c = 2*tid;
  const bool wedge = (l == 63) && (tid != 255);  // wave edge: global neighbor
  const bool tlast = (tid == 255);               // col 511: no f_v
  const int h0 = b*64;

  float v00=0.f,v01=0.f,v02=0.f, v10=0.f,v11=0.f,v12=0.f;
  float h00=0.f,h01=0.f,h02=0.f, h10=0.f,h11=0.f,h12=0.f;

  float2 xc = *(const float2*)(xp + (size_t)h0*512 + c);
  float2 rc = *(const float2*)(rp + (size_t)h0*512 + c);

  #pragma unroll 2
  for (int k = 0; k < 64; ++k){
    const int h = h0 + k;
    // f_v on row h (all rows)
    float xn1 = __shfl(xc.x, nl, 64);
    float rn1 = __shfl(rc.x, nl, 64);
    if (wedge){
      xn1 = xp[(size_t)h*512 + c + 2];
      rn1 = rp[(size_t)h*512 + c + 2];
    }
    const float dv0 = xc.x - xc.y, ev0 = rc.x - rc.y;
    v00 = fmaf(dv0,ev0,v00); v01 = fmaf(dv0,dv0,v01); v02 = fmaf(ev0,ev0,v02);
    if (!tlast){
      const float dv1 = xc.y - xn1, ev1 = rc.y - rn1;
      v10 = fmaf(dv1,ev1,v10); v11 = fmaf(dv1,dv1,v11); v12 = fmaf(ev1,ev1,v12);
    }
    // f_h pairing rows (h, h+1), rows 0..510 only
    if (h < 511){
      const float2 nx = *(const float2*)(xp + (size_t)(h+1)*512 + c);
      const float2 nr = *(const float2*)(rp + (size_t)(h+1)*512 + c);
      const float dh0 = xc.x - nx.x, eh0 = rc.x - nr.x;
      const float dh1 = xc.y - nx.y, eh1 = rc.y - nr.y;
      h00 = fmaf(dh0,eh0,h00); h01 = fmaf(dh0,dh0,h01); h02 = fmaf(eh0,eh0,h02);
      h10 = fmaf(dh1,eh1,h10); h11 = fmaf(dh1,dh1,h11); h12 = fmaf(eh1,eh1,h12);
      xc = nx; rc = nr;
    }
  }

  float* slot = colPart + (size_t)bid * (6*512);
  *(float2*)(slot + 0*512 + c) = make_float2(v00, v10);
  *(float2*)(slot + 1*512 + c) = make_float2(v01, v11);
  *(float2*)(slot + 2*512 + c) = make_float2(v02, v12);
  *(float2*)(slot + 3*512 + c) = make_float2(h00, h10);
  *(float2*)(slot + 4*512 + c) = make_float2(h01, h11);
  *(float2*)(slot + 5*512 + c) = make_float2(h02, h12);
}

// ---------------- finish: reduce col partials over 8 bands -------------------
__global__ __launch_bounds__(256) void gp_cols(
    const float* __restrict__ colPart, double* __restrict__ dblk)
{
  const int p = blockIdx.x >> 1;
  const int f = blockIdx.x & 1;    // 0 = fv, 1 = fh
  const int tid = threadIdx.x;
  double acc = 0.0;
  for (int c = tid; c < 512; c += 256){
    float d = 0.f, a = 0.f, b = 0.f;
    #pragma unroll
    for (int s = 0; s < 8; ++s){
      const float* sp = colPart + ((size_t)(p*8 + s) * 6 + f*3) * 512;
      d += sp[c]; a += sp[512 + c]; b += sp[1024 + c];
    }
    acc += (double)cos_sim(d, a, b);   // fv col 511: cos(0,0,0)=0, harmless
  }
  #pragma unroll
  for (int m = 1; m < 64; m <<= 1) acc += __shfl_xor(acc, m, 64);
  __shared__ double ls[4];
  const int w = tid >> 6, l = tid & 63;
  if (l == 0) ls[w] = acc;
  __syncthreads();
  if (tid == 0) dblk[blockIdx.x] = ls[0] + ls[1] + ls[2] + ls[3];
}

__global__ __launch_bounds__(256) void gp_fin(
    const double* __restrict__ dblk, const float* __restrict__ rowPart,
    int nblk, float* __restrict__ out)
{
  const int tid = threadIdx.x;
  double rv = 0, rh = 0, cv = 0, ch = 0;
  for (int i = tid; i < nblk; i += 256){
    rv += (double)rowPart[2*i];
    rh += (double)rowPart[2*i+1];
  }
  for (int i = tid; i < 192; i += 256){
    if (i & 1) ch += dblk[i]; else cv += dblk[i];
  }
  #pragma unroll
  for (int m = 1; m < 64; m <<= 1){
    rv += __shfl_xor(rv, m, 64); rh += __shfl_xor(rh, m, 64);
    cv += __shfl_xor(cv, m, 64); ch += __shfl_xor(ch, m, 64);
  }
  __shared__ double ls[4][4];
  const int w = tid >> 6, l = tid & 63;
  if (l == 0){ ls[w][0]=rv; ls[w][1]=rh; ls[w][2]=cv; ls[w][3]=ch; }
  __syncthreads();
  if (tid == 0){
    double RV=0, RH=0, CV=0, CH=0;
    #pragma unroll
    for (int i = 0; i < 4; ++i){ RV+=ls[i][0]; RH+=ls[i][1]; CV+=ls[i][2]; CH+=ls[i][3]; }
    const double t = RV/512.0 + RH/511.0 + CV/511.0 + CH/512.0;
    out[0] = (float)(-t / 32.0);
  }
}

extern "C" void kernel_launch(void* const* d_in, const int* in_sizes, int n_in,
                              void* d_out, int out_size, void* d_ws, size_t ws_size,
                              hipStream_t stream) {
  const float* X = (const float*)d_in[0];
  const float* R = (const float*)d_in[1];
  float* out = (float*)d_out;

  float*  colPart = (float*)d_ws;                        // 768*6*512 f32
  float*  rowPart = colPart + (size_t)768*6*512;         // 768*2 f32
  double* dblk    = (double*)(rowPart + (size_t)768*2);  // 192 f64

  gp_rows  <<<dim3(768), dim3(256), 0, stream>>>(X, R, rowPart);
  gp_colacc<<<dim3(768), dim3(256), 0, stream>>>(X, R, colPart);
  gp_cols  <<<dim3(192), dim3(256), 0, stream>>>(colPart, dblk);
  gp_fin   <<<dim3(1),   dim3(256), 0, stream>>>(dblk, rowPart, 768, out);
}

// Round 5
// 81.967 us; speedup vs baseline: 2.2174x; 1.0424x over previous
//
#include <hip/hip_runtime.h>

// GPLoss: gradient-profile loss, scalar output. Fused single main dispatch:
//   blocks [0,1536): row cosines, 96 planes x 16 strips (wave = 8 rows + halo)
//   blocks [1536,2304): column partial stats, 96 planes x 8 bands (64 rows)
// ws: colPart f32[768][6][512] (9.44 MB) ; rowPart f32[1536][2] ; dblk f64[192]

__device__ __forceinline__ float cos_sim(float dot, float sx, float sr){
  float nx = fmaxf(sqrtf(sx), 1e-12f);
  float nr = fmaxf(sqrtf(sr), 1e-12f);
  return dot / (nx * nr);
}

__global__ __launch_bounds__(256) void gp_fused(
    const float* __restrict__ X, const float* __restrict__ R,
    float* __restrict__ rowPart, float* __restrict__ colPart)
{
  const int tid = threadIdx.x;
  const int l = tid & 63;

  if (blockIdx.x < 1536){
    // ---------------- rows part: NS=16, wave owns 8 rows (+1 halo) ----------
    const int bid = blockIdx.x;
    const int p = bid >> 4, s = bid & 15;
    const int w = tid >> 6;
    const size_t plane = (size_t)p * (512u*512u);
    const float* xp = X + plane;
    const float* rp = R + plane;
    const int base = s*32 + w*8;
    const int c0 = 8*l;
    const int nl = (l+1) & 63;
    const bool lastlane = (l == 63);

    float rsv = 0.f, rsh = 0.f;

    const float* xr = xp + (size_t)base*512 + c0;
    const float* rr = rp + (size_t)base*512 + c0;
    float4 xa = *(const float4*)xr, xb = *(const float4*)(xr+4);
    float4 ra = *(const float4*)rr, rb = *(const float4*)(rr+4);

    #pragma unroll 2
    for (int k = 0; k < 8; ++k){
      const int h  = base + k;
      const int hn = (h+1 < 512) ? h+1 : 511;
      const float* xn = xp + (size_t)hn*512 + c0;
      const float* rn = rp + (size_t)hn*512 + c0;
      const float4 nxa = *(const float4*)xn, nxb = *(const float4*)(xn+4);
      const float4 nra = *(const float4*)rn, nrb = *(const float4*)(rn+4);

      const float nX = __shfl(xa.x, nl, 64);
      const float nR = __shfl(ra.x, nl, 64);

      const float aX[8] = {xa.x,xa.y,xa.z,xa.w, xb.x,xb.y,xb.z,xb.w};
      const float aR[8] = {ra.x,ra.y,ra.z,ra.w, rb.x,rb.y,rb.z,rb.w};
      const float bX[8] = {nxa.x,nxa.y,nxa.z,nxa.w, nxb.x,nxb.y,nxb.z,nxb.w};
      const float bR[8] = {nra.x,nra.y,nra.z,nra.w, nrb.x,nrb.y,nrb.z,nrb.w};

      float s0=0.f,s1=0.f,s2=0.f,s3=0.f,s4=0.f,s5=0.f;
      #pragma unroll
      for (int j = 0; j < 8; ++j){
        const float dv = (j<7) ? (aX[j]-aX[j+1]) : (lastlane ? 0.f : aX[7]-nX);
        const float ev = (j<7) ? (aR[j]-aR[j+1]) : (lastlane ? 0.f : aR[7]-nR);
        s0 = fmaf(dv,ev,s0); s1 = fmaf(dv,dv,s1); s2 = fmaf(ev,ev,s2);
        const float dh = aX[j]-bX[j];     // h==511: b==a -> 0, discarded below
        const float eh = aR[j]-bR[j];
        s3 = fmaf(dh,eh,s3); s4 = fmaf(dh,dh,s4); s5 = fmaf(eh,eh,s5);
      }
      #pragma unroll
      for (int m = 1; m < 64; m <<= 1){   // 6 independent chains, ILP=6
        s0 += __shfl_xor(s0,m,64); s1 += __shfl_xor(s1,m,64); s2 += __shfl_xor(s2,m,64);
        s3 += __shfl_xor(s3,m,64); s4 += __shfl_xor(s4,m,64); s5 += __shfl_xor(s5,m,64);
      }
      rsv += cos_sim(s0,s1,s2);
      if (h < 511) rsh += cos_sim(s3,s4,s5);
      xa=nxa; xb=nxb; ra=nra; rb=nrb;
    }

    __shared__ float rs[4][2];
    if (l == 0){ rs[w][0]=rsv; rs[w][1]=rsh; }
    __syncthreads();
    if (tid == 0){
      rowPart[2*bid+0] = rs[0][0]+rs[1][0]+rs[2][0]+rs[3][0];
      rowPart[2*bid+1] = rs[0][1]+rs[1][1]+rs[2][1]+rs[3][1];
    }
  } else {
    // ---------------- colacc part: 96 planes x 8 bands, thread owns 2 cols --
    const int bid = blockIdx.x - 1536;
    const int p = bid >> 3, b = bid & 7;
    const int nl = (l+1) & 63;
    const size_t plane = (size_t)p * (512u*512u);
    const float* xp = X + plane;
    const float* rp = R + plane;
    const int c = 2*tid;
    const bool wedge = (l == 63) && (tid != 255);  // wave edge: global neighbor
    const bool tlast = (tid == 255);               // col 511: no f_v
    const int h0 = b*64;

    float v00=0.f,v01=0.f,v02=0.f, v10=0.f,v11=0.f,v12=0.f;
    float h00=0.f,h01=0.f,h02=0.f, h10=0.f,h11=0.f,h12=0.f;

    float2 xc = *(const float2*)(xp + (size_t)h0*512 + c);
    float2 rc = *(const float2*)(rp + (size_t)h0*512 + c);

    #pragma unroll 2
    for (int k = 0; k < 64; ++k){
      const int h = h0 + k;
      float xn1 = __shfl(xc.x, nl, 64);
      float rn1 = __shfl(rc.x, nl, 64);
      if (wedge){
        xn1 = xp[(size_t)h*512 + c + 2];
        rn1 = rp[(size_t)h*512 + c + 2];
      }
      const float dv0 = xc.x - xc.y, ev0 = rc.x - rc.y;
      v00 = fmaf(dv0,ev0,v00); v01 = fmaf(dv0,dv0,v01); v02 = fmaf(ev0,ev0,v02);
      if (!tlast){
        const float dv1 = xc.y - xn1, ev1 = rc.y - rn1;
        v10 = fmaf(dv1,ev1,v10); v11 = fmaf(dv1,dv1,v11); v12 = fmaf(ev1,ev1,v12);
      }
      if (h < 511){
        const float2 nx = *(const float2*)(xp + (size_t)(h+1)*512 + c);
        const float2 nr = *(const float2*)(rp + (size_t)(h+1)*512 + c);
        const float dh0 = xc.x - nx.x, eh0 = rc.x - nr.x;
        const float dh1 = xc.y - nx.y, eh1 = rc.y - nr.y;
        h00 = fmaf(dh0,eh0,h00); h01 = fmaf(dh0,dh0,h01); h02 = fmaf(eh0,eh0,h02);
        h10 = fmaf(dh1,eh1,h10); h11 = fmaf(dh1,dh1,h11); h12 = fmaf(eh1,eh1,h12);
        xc = nx; rc = nr;
      }
    }

    float* slot = colPart + (size_t)bid * (6*512);
    *(float2*)(slot + 0*512 + c) = make_float2(v00, v10);
    *(float2*)(slot + 1*512 + c) = make_float2(v01, v11);
    *(float2*)(slot + 2*512 + c) = make_float2(v02, v12);
    *(float2*)(slot + 3*512 + c) = make_float2(h00, h10);
    *(float2*)(slot + 4*512 + c) = make_float2(h01, h11);
    *(float2*)(slot + 5*512 + c) = make_float2(h02, h12);
  }
}

// ---------------- finish: reduce col partials over 8 bands -------------------
__global__ __launch_bounds__(256) void gp_cols(
    const float* __restrict__ colPart, double* __restrict__ dblk)
{
  const int p = blockIdx.x >> 1;
  const int f = blockIdx.x & 1;    // 0 = fv, 1 = fh
  const int tid = threadIdx.x;
  double acc = 0.0;
  for (int c = tid; c < 512; c += 256){
    float d = 0.f, a = 0.f, b = 0.f;
    #pragma unroll
    for (int s = 0; s < 8; ++s){
      const float* sp = colPart + ((size_t)(p*8 + s) * 6 + f*3) * 512;
      d += sp[c]; a += sp[512 + c]; b += sp[1024 + c];
    }
    acc += (double)cos_sim(d, a, b);   // fv col 511: cos(0,0,0)=0, harmless
  }
  #pragma unroll
  for (int m = 1; m < 64; m <<= 1) acc += __shfl_xor(acc, m, 64);
  __shared__ double ls[4];
  const int w = tid >> 6, l = tid & 63;
  if (l == 0) ls[w] = acc;
  __syncthreads();
  if (tid == 0) dblk[blockIdx.x] = ls[0] + ls[1] + ls[2] + ls[3];
}

__global__ __launch_bounds__(256) void gp_fin(
    const double* __restrict__ dblk, const float* __restrict__ rowPart,
    int nblk, float* __restrict__ out)
{
  const int tid = threadIdx.x;
  double rv = 0, rh = 0, cv = 0, ch = 0;
  for (int i = tid; i < nblk; i += 256){
    rv += (double)rowPart[2*i];
    rh += (double)rowPart[2*i+1];
  }
  for (int i = tid; i < 192; i += 256){
    if (i & 1) ch += dblk[i]; else cv += dblk[i];
  }
  #pragma unroll
  for (int m = 1; m < 64; m <<= 1){
    rv += __shfl_xor(rv, m, 64); rh += __shfl_xor(rh, m, 64);
    cv += __shfl_xor(cv, m, 64); ch += __shfl_xor(ch, m, 64);
  }
  __shared__ double ls[4][4];
  const int w = tid >> 6, l = tid & 63;
  if (l == 0){ ls[w][0]=rv; ls[w][1]=rh; ls[w][2]=cv; ls[w][3]=ch; }
  __syncthreads();
  if (tid == 0){
    double RV=0, RH=0, CV=0, CH=0;
    #pragma unroll
    for (int i = 0; i < 4; ++i){ RV+=ls[i][0]; RH+=ls[i][1]; CV+=ls[i][2]; CH+=ls[i][3]; }
    const double t = RV/512.0 + RH/511.0 + CV/511.0 + CH/512.0;
    out[0] = (float)(-t / 32.0);
  }
}

extern "C" void kernel_launch(void* const* d_in, const int* in_sizes, int n_in,
                              void* d_out, int out_size, void* d_ws, size_t ws_size,
                              hipStream_t stream) {
  const float* X = (const float*)d_in[0];
  const float* R = (const float*)d_in[1];
  float* out = (float*)d_out;

  float*  colPart = (float*)d_ws;                        // 768*6*512 f32
  float*  rowPart = colPart + (size_t)768*6*512;         // 1536*2 f32
  double* dblk    = (double*)(rowPart + (size_t)1536*2); // 192 f64

  gp_fused<<<dim3(2304), dim3(256), 0, stream>>>(X, R, rowPart, colPart);
  gp_cols <<<dim3(192),  dim3(256), 0, stream>>>(colPart, dblk);
  gp_fin  <<<dim3(1),    dim3(256), 0, stream>>>(dblk, rowPart, 1536, out);
}

// Round 6
// 63.200 us; speedup vs baseline: 2.8759x; 1.2969x over previous
//
#include <hip/hip_runtime.h>

// GPLoss: gradient-profile loss, scalar output. Single-read unified main pass.
// Block = 256 thr, one 32-row band of one plane; thread owns cols {2t, 2t+1}.
// Row stats reduced in-wave via DPP (VALU pipe, no LDS ops), cross-wave via
// 3 KB LDS staging. Col stats pure per-thread -> colPart slots (atomic-free).
// ws: colPart f32[96*NB][6][512] ; rowPart f32[96*NB][2] ; dblk f64[192]

#define DPP_ADD(x, ctrl, rmask) \
  x += __int_as_float(__builtin_amdgcn_update_dpp(0, __float_as_int(x), ctrl, rmask, 0xf, false))

__device__ __forceinline__ float wave_dpp_sum(float x){
  DPP_ADD(x, 0x111, 0xf);   // row_shr:1
  DPP_ADD(x, 0x112, 0xf);   // row_shr:2
  DPP_ADD(x, 0x114, 0xf);   // row_shr:4
  DPP_ADD(x, 0x118, 0xf);   // row_shr:8
  DPP_ADD(x, 0x142, 0xa);   // row_bcast:15 -> rows 1,3
  DPP_ADD(x, 0x143, 0xc);   // row_bcast:31 -> rows 2,3
  return x;                 // lane 63 holds the 64-lane sum
}

__device__ __forceinline__ float cos_sim(float dot, float sx, float sr){
  float nx = fmaxf(sqrtf(sx), 1e-12f);
  float nr = fmaxf(sqrtf(sr), 1e-12f);
  return dot / (nx * nr);
}

template<int RB>   // rows per band (32 preferred, 64 fallback); NB = 512/RB
__global__ __launch_bounds__(256) void gp_uni(
    const float* __restrict__ X, const float* __restrict__ R,
    float* __restrict__ rowPart, float* __restrict__ colPart)
{
  constexpr int NB = 512 / RB;
  const int bid = blockIdx.x;
  const int p = bid / NB, b = bid % NB;
  const int tid = threadIdx.x, w = tid >> 6, l = tid & 63;
  const size_t plane = (size_t)p * (512u*512u);
  const float* xp = X + plane;
  const float* rp = R + plane;
  const int c  = 2*tid;
  const int cn = (c+2 < 512) ? c+2 : 511;   // f_v neighbor col (clamped)
  const bool tlast = (tid == 255);           // col 511: no f_v diff
  const int h0 = b * RB;

  __shared__ float rowbuf[RB][4][6];

  float v00=0.f,v01=0.f,v02=0.f, v10=0.f,v11=0.f,v12=0.f;
  float h00=0.f,h01=0.f,h02=0.f, h10=0.f,h11=0.f,h12=0.f;

  const float* xr0 = xp + (size_t)h0*512;
  const float* rr0 = rp + (size_t)h0*512;
  float2 xc = *(const float2*)(xr0 + c);
  float2 rc = *(const float2*)(rr0 + c);
  float  xn = xr0[cn], rn = rr0[cn];

  #pragma unroll 2
  for (int k = 0; k < RB; ++k){
    const int h  = h0 + k;
    const int hn = (h+1 < 512) ? h+1 : 511;   // h==511: next==cur -> dh=0
    const float* xr = xp + (size_t)hn*512;
    const float* rr = rp + (size_t)hn*512;
    const float2 nx  = *(const float2*)(xr + c);
    const float2 nr  = *(const float2*)(rr + c);
    const float  nxn = xr[cn], nrn = rr[cn];

    // ---- f_v on row h (cols c->c+1, c+1->c+2)
    const float dv0 = xc.x - xc.y, ev0 = rc.x - rc.y;
    float dv1 = xc.y - xn,         ev1 = rc.y - rn;
    if (tlast){ dv1 = 0.f; ev1 = 0.f; }
    v00 = fmaf(dv0,ev0,v00); v01 = fmaf(dv0,dv0,v01); v02 = fmaf(ev0,ev0,v02);
    v10 = fmaf(dv1,ev1,v10); v11 = fmaf(dv1,dv1,v11); v12 = fmaf(ev1,ev1,v12);
    float pv0 = dv0*ev0; pv0 = fmaf(dv1,ev1,pv0);
    float pv1 = dv0*dv0; pv1 = fmaf(dv1,dv1,pv1);
    float pv2 = ev0*ev0; pv2 = fmaf(ev1,ev1,pv2);

    // ---- f_h rows (h, h+1) — h==511 contributes exact zeros
    const float dh0 = xc.x - nx.x, eh0 = rc.x - nr.x;
    const float dh1 = xc.y - nx.y, eh1 = rc.y - nr.y;
    h00 = fmaf(dh0,eh0,h00); h01 = fmaf(dh0,dh0,h01); h02 = fmaf(eh0,eh0,h02);
    h10 = fmaf(dh1,eh1,h10); h11 = fmaf(dh1,dh1,h11); h12 = fmaf(eh1,eh1,h12);
    float ph0 = dh0*eh0; ph0 = fmaf(dh1,eh1,ph0);
    float ph1 = dh0*dh0; ph1 = fmaf(dh1,dh1,ph1);
    float ph2 = eh0*eh0; ph2 = fmaf(eh1,eh1,ph2);

    // ---- in-wave row reduction on the VALU pipe (6 independent DPP chains)
    pv0 = wave_dpp_sum(pv0); pv1 = wave_dpp_sum(pv1); pv2 = wave_dpp_sum(pv2);
    ph0 = wave_dpp_sum(ph0); ph1 = wave_dpp_sum(ph1); ph2 = wave_dpp_sum(ph2);
    if (l == 63){
      rowbuf[k][w][0]=pv0; rowbuf[k][w][1]=pv1; rowbuf[k][w][2]=pv2;
      rowbuf[k][w][3]=ph0; rowbuf[k][w][4]=ph1; rowbuf[k][w][5]=ph2;
    }

    xc = nx; rc = nr; xn = nxn; rn = nrn;
  }

  // ---- col partials: pure per-thread, atomic-free slot store
  float* slot = colPart + (size_t)bid * (6*512);
  *(float2*)(slot + 0*512 + c) = make_float2(v00, v10);
  *(float2*)(slot + 1*512 + c) = make_float2(v01, v11);
  *(float2*)(slot + 2*512 + c) = make_float2(v02, v12);
  *(float2*)(slot + 3*512 + c) = make_float2(h00, h10);
  *(float2*)(slot + 4*512 + c) = make_float2(h01, h11);
  *(float2*)(slot + 5*512 + c) = make_float2(h02, h12);

  // ---- row finalize: combine 4 waves per row, cos, block sum (wave 0 only)
  __syncthreads();
  if (tid < 64){
    float rv = 0.f, rh = 0.f;
    if (tid < RB){
      const int h = h0 + tid;
      float a0=0.f,a1=0.f,a2=0.f,b0=0.f,b1=0.f,b2=0.f;
      #pragma unroll
      for (int q = 0; q < 4; ++q){
        a0 += rowbuf[tid][q][0]; a1 += rowbuf[tid][q][1]; a2 += rowbuf[tid][q][2];
        b0 += rowbuf[tid][q][3]; b1 += rowbuf[tid][q][4]; b2 += rowbuf[tid][q][5];
      }
      rv = cos_sim(a0,a1,a2);
      rh = (h < 511) ? cos_sim(b0,b1,b2) : 0.f;
    }
    rv = wave_dpp_sum(rv);
    rh = wave_dpp_sum(rh);
    if (tid == 63){
      rowPart[2*bid+0] = rv;
      rowPart[2*bid+1] = rh;
    }
  }
}

// ---------------- finish: reduce col partials over NB bands ------------------
template<int NB>
__global__ __launch_bounds__(256) void gp_cols(
    const float* __restrict__ colPart, double* __restrict__ dblk)
{
  const int p = blockIdx.x >> 1;
  const int f = blockIdx.x & 1;    // 0 = fv, 1 = fh
  const int tid = threadIdx.x;
  double acc = 0.0;
  for (int c = tid; c < 512; c += 256){
    float d = 0.f, a = 0.f, b = 0.f;
    #pragma unroll
    for (int s = 0; s < NB; ++s){
      const float* sp = colPart + ((size_t)(p*NB + s) * 6 + f*3) * 512;
      d += sp[c]; a += sp[512 + c]; b += sp[1024 + c];
    }
    acc += (double)cos_sim(d, a, b);   // fv col 511: cos(0,0,0)=0, harmless
  }
  #pragma unroll
  for (int m = 1; m < 64; m <<= 1) acc += __shfl_xor(acc, m, 64);
  __shared__ double ls[4];
  const int w = tid >> 6, l = tid & 63;
  if (l == 0) ls[w] = acc;
  __syncthreads();
  if (tid == 0) dblk[blockIdx.x] = ls[0] + ls[1] + ls[2] + ls[3];
}

__global__ __launch_bounds__(256) void gp_fin(
    const double* __restrict__ dblk, const float* __restrict__ rowPart,
    int nblk, float* __restrict__ out)
{
  const int tid = threadIdx.x;
  double rv = 0, rh = 0, cv = 0, ch = 0;
  for (int i = tid; i < nblk; i += 256){
    rv += (double)rowPart[2*i];
    rh += (double)rowPart[2*i+1];
  }
  for (int i = tid; i < 192; i += 256){
    if (i & 1) ch += dblk[i]; else cv += dblk[i];
  }
  #pragma unroll
  for (int m = 1; m < 64; m <<= 1){
    rv += __shfl_xor(rv, m, 64); rh += __shfl_xor(rh, m, 64);
    cv += __shfl_xor(cv, m, 64); ch += __shfl_xor(ch, m, 64);
  }
  __shared__ double ls[4][4];
  const int w = tid >> 6, l = tid & 63;
  if (l == 0){ ls[w][0]=rv; ls[w][1]=rh; ls[w][2]=cv; ls[w][3]=ch; }
  __syncthreads();
  if (tid == 0){
    double RV=0, RH=0, CV=0, CH=0;
    #pragma unroll
    for (int i = 0; i < 4; ++i){ RV+=ls[i][0]; RH+=ls[i][1]; CV+=ls[i][2]; CH+=ls[i][3]; }
    const double t = RV/512.0 + RH/511.0 + CV/511.0 + CH/512.0;
    out[0] = (float)(-t / 32.0);
  }
}

extern "C" void kernel_launch(void* const* d_in, const int* in_sizes, int n_in,
                              void* d_out, int out_size, void* d_ws, size_t ws_size,
                              hipStream_t stream) {
  const float* X = (const float*)d_in[0];
  const float* R = (const float*)d_in[1];
  float* out = (float*)d_out;

  const size_t need16 = (size_t)96*16*6*512*4 + (size_t)96*16*2*4 + 192*8;

  if (ws_size >= need16){
    constexpr int NB = 16;                                 // 32-row bands
    float*  colPart = (float*)d_ws;
    float*  rowPart = colPart + (size_t)96*NB*6*512;
    double* dblk    = (double*)(rowPart + (size_t)96*NB*2);
    gp_uni<32><<<dim3(96*NB), dim3(256), 0, stream>>>(X, R, rowPart, colPart);
    gp_cols<NB><<<dim3(192),  dim3(256), 0, stream>>>(colPart, dblk);
    gp_fin     <<<dim3(1),    dim3(256), 0, stream>>>(dblk, rowPart, 96*NB, out);
  } else {
    constexpr int NB = 8;                                  // 64-row bands
    float*  colPart = (float*)d_ws;
    float*  rowPart = colPart + (size_t)96*NB*6*512;
    double* dblk    = (double*)(rowPart + (size_t)96*NB*2);
    gp_uni<64><<<dim3(96*NB), dim3(256), 0, stream>>>(X, R, rowPart, colPart);
    gp_cols<NB><<<dim3(192),  dim3(256), 0, stream>>>(colPart, dblk);
    gp_fin     <<<dim3(1),    dim3(256), 0, stream>>>(dblk, rowPart, 96*NB, out);
  }
}